// Round 3
// baseline (372.196 us; speedup 1.0000x reference)
//
#include <hip/hip_runtime.h>
#include <hip/hip_bf16.h>

#define CH 512
#define TT 1024
#define NH 8
#define HCH 64

typedef unsigned short u16;
typedef unsigned int u32;
typedef __attribute__((ext_vector_type(8))) __bf16 bf16x8;
typedef __attribute__((ext_vector_type(4))) float f32x4;

__device__ inline u16 f2bf(float x) {
  union { __hip_bfloat16 b; u16 u; } v; v.b = __float2bfloat16(x); return v.u;
}

#define AS1 __attribute__((address_space(1)))
#define AS3 __attribute__((address_space(3)))
__device__ inline void gld_lds16(const void* src, void* dst) {
  __builtin_amdgcn_global_load_lds((const AS1 u32*)src, (AS3 u32*)dst, 16, 0, 0);
}

// ---------------- weight cast fp32 -> bf16 ----------------
__global__ __launch_bounds__(256) void castw_kernel(
    const float* __restrict__ wq, const float* __restrict__ wp,
    u16* __restrict__ wqb, u16* __restrict__ wpb) {
  int i = blockIdx.x * 256 + threadIdx.x;
  if (i < 3 * CH * CH) wqb[i] = f2bf(wq[i]);
  if (i < CH * CH) wpb[i] = f2bf(wp[i]);
}

// ---------------- GroupNorm -> channels-last bf16 ----------------
__global__ __launch_bounds__(256) void gn_kernel(
    const float* __restrict__ x, const float* __restrict__ gamma,
    const float* __restrict__ beta, u16* __restrict__ xn) {
  int b = blockIdx.x >> 5, g = blockIdx.x & 31;
  const float* xp = x + ((size_t)(b * CH + g * 16)) * TT;
  int tid = threadIdx.x;
  float s = 0.f, s2 = 0.f;
  for (int i = tid; i < 16 * TT; i += 256) {
    float v = xp[i]; s += v; s2 += v * v;
  }
  for (int o = 32; o; o >>= 1) { s += __shfl_down(s, o); s2 += __shfl_down(s2, o); }
  __shared__ float red[8];
  int wid = tid >> 6;
  if ((tid & 63) == 0) { red[wid] = s; red[wid + 4] = s2; }
  __syncthreads();
  s = red[0] + red[1] + red[2] + red[3];
  s2 = red[4] + red[5] + red[6] + red[7];
  const float invN = 1.f / (16.f * TT);
  float mean = s * invN;
  float rstd = rsqrtf(fmaxf(s2 * invN - mean * mean, 0.f) + 1e-5f);
  float ga[16], be[16];
#pragma unroll
  for (int c = 0; c < 16; c++) {
    float gg = gamma[g * 16 + c] * rstd;
    ga[c] = gg; be[c] = beta[g * 16 + c] - mean * gg;
  }
  for (int t = tid; t < TT; t += 256) {
    union { u16 v[16]; uint4 q[2]; } pk;
#pragma unroll
    for (int c = 0; c < 16; c++) pk.v[c] = f2bf(xp[c * TT + t] * ga[c] + be[c]);
    u16* dst = xn + ((size_t)(b * TT + t)) * CH + g * 16;
    *(uint4*)dst = pk.q[0];
    *(uint4*)(dst + 8) = pk.q[1];
  }
}

// ---------------- GEMM helpers ----------------
// LDS tile: [128 rows][4 slots x 16B], swizzle slot ^= (row>>1)&3, rows stride CH elems in global
__device__ inline void stage512(const u16* grow0, char* ldsb, int tid) {
#pragma unroll
  for (int r = 0; r < 2; r++) {
    int chunk = tid + r * 256;
    int row = chunk >> 2;
    int slot = (chunk & 3) ^ ((row >> 1) & 3);
    gld_lds16((const char*)(grow0 + (size_t)row * CH) + slot * 16, ldsb + chunk * 16);
  }
}
__device__ inline bf16x8 frag512(const char* ldsb, int row, int g) {
  int slot = g ^ ((row >> 1) & 3);
  return *(const bf16x8*)(ldsb + row * 64 + slot * 16);
}

// EPI 0: qkv epilogue (scatter q/k channels-last per head, v channel-major)
// EPI 1: proj epilogue (residual + bias, fp32 out)
template <int EPI>
__global__ __launch_bounds__(256) void gemm_kernel(
    const u16* __restrict__ A, const u16* __restrict__ B,
    const float* __restrict__ bias, const float* __restrict__ xres,
    u16* __restrict__ q_cl, u16* __restrict__ k_cl, u16* __restrict__ v_cm,
    float* __restrict__ outp, int Mtiles) {
  __shared__ char lds[32768];
  int tid = threadIdx.x;
  int mt = blockIdx.x % Mtiles, nt = blockIdx.x / Mtiles;
  const u16* Ab = A + (size_t)mt * 128 * CH;
  const u16* Bb = B + (size_t)nt * 128 * CH;
  int lane = tid & 63, wid = tid >> 6;
  int g = lane >> 4, r15 = lane & 15;
  int wrow = (wid >> 1) * 64, wcol = (wid & 1) * 64;
  f32x4 acc[4][4] = {};
  stage512(Ab, lds, tid);
  stage512(Bb, lds + 8192, tid);
  __syncthreads();
  for (int kt = 0; kt < CH / 32; kt++) {
    int cur = kt & 1;
    char* Ac = lds + cur * 16384;
    char* Bc = lds + 8192 + cur * 16384;
    if (kt + 1 < CH / 32) {
      char* An = lds + (cur ^ 1) * 16384;
      stage512(Ab + (kt + 1) * 32, An, tid);
      stage512(Bb + (kt + 1) * 32, An + 8192, tid);
    }
    bf16x8 af[4], bfr[4];
#pragma unroll
    for (int i = 0; i < 4; i++) af[i] = frag512(Ac, wrow + i * 16 + r15, g);
#pragma unroll
    for (int j = 0; j < 4; j++) bfr[j] = frag512(Bc, wcol + j * 16 + r15, g);
#pragma unroll
    for (int i = 0; i < 4; i++)
#pragma unroll
      for (int j = 0; j < 4; j++)
        acc[i][j] = __builtin_amdgcn_mfma_f32_16x16x32_bf16(af[i], bfr[j], acc[i][j], 0, 0, 0);
    __syncthreads();
  }
  int m0 = mt * 128 + wrow;
  if (EPI == 0) {
    int type = (m0 >> 6) % 3;
    int h = m0 / 192;
#pragma unroll
    for (int i = 0; i < 4; i++) {
      float bv[4];
#pragma unroll
      for (int r = 0; r < 4; r++) bv[r] = bias[m0 + i * 16 + g * 4 + r];
#pragma unroll
      for (int j = 0; j < 4; j++) {
        int n = nt * 128 + wcol + j * 16 + r15;
        int t = n & (TT - 1);
        int bh = (n >> 10) * NH + h;
        if (type == 2) {
#pragma unroll
          for (int r = 0; r < 4; r++) {
            int cp = i * 16 + g * 4 + r;
            v_cm[((size_t)bh * HCH + cp) * TT + t] = f2bf(acc[i][j][r] + bv[r]);
          }
        } else {
          union { u16 v[4]; uint2 u; } pk;
#pragma unroll
          for (int r = 0; r < 4; r++) pk.v[r] = f2bf(acc[i][j][r] + bv[r]);
          u16* dst = (type == 0 ? q_cl : k_cl) + ((size_t)bh * TT + t) * HCH + i * 16 + g * 4;
          *(uint2*)dst = pk.u;
        }
      }
    }
  } else {
#pragma unroll
    for (int i = 0; i < 4; i++) {
      float bv[4];
#pragma unroll
      for (int r = 0; r < 4; r++) bv[r] = bias[m0 + i * 16 + g * 4 + r];
#pragma unroll
      for (int j = 0; j < 4; j++) {
        int n = nt * 128 + wcol + j * 16 + r15;
        int t = n & (TT - 1);
        int bb = n >> 10;
#pragma unroll
        for (int r = 0; r < 4; r++) {
          size_t oi = ((size_t)bb * CH + m0 + i * 16 + g * 4 + r) * TT + t;
          outp[oi] = xres[oi] + acc[i][j][r] + bv[r];
        }
      }
    }
  }
}

// ---------------- flash attention ----------------
__global__ __launch_bounds__(256) void attn_kernel(
    const u16* __restrict__ q_cl, const u16* __restrict__ k_cl,
    const u16* __restrict__ v_cm, u16* __restrict__ a_cl) {
  int bh = blockIdx.x >> 3;
  int t0 = (blockIdx.x & 7) * 128;
  __shared__ char Qs[16384];
  __shared__ char Ks[8192];
  __shared__ char Vs[8192];
  __shared__ char Ps[16384];
  int tid = threadIdx.x, lane = tid & 63, wid = tid >> 6;
  int g = lane >> 4, r15 = lane & 15;
  const u16* qb = q_cl + ((size_t)bh * TT + t0) * HCH;
#pragma unroll
  for (int r = 0; r < 4; r++) {
    int chunk = tid + r * 256;
    int row = chunk >> 3;
    int slot = (chunk & 7) ^ (row & 7);
    gld_lds16((const char*)(qb + (size_t)row * HCH) + slot * 16, Qs + chunk * 16);
  }
  __syncthreads();
  bf16x8 qf[2][2];
#pragma unroll
  for (int tb = 0; tb < 2; tb++)
#pragma unroll
    for (int ks = 0; ks < 2; ks++) {
      int row = wid * 32 + tb * 16 + r15;
      int slot = (ks * 4 + g) ^ (row & 7);
      qf[tb][ks] = *(const bf16x8*)(Qs + row * 128 + slot * 16);
    }
  f32x4 oacc[2][4] = {};
  float mrow[2][4], lrow[2][4];
#pragma unroll
  for (int tb = 0; tb < 2; tb++)
#pragma unroll
    for (int r = 0; r < 4; r++) { mrow[tb][r] = -3.0e38f; lrow[tb][r] = 0.f; }
  char* Pw = Ps + wid * 4096;
  const float SC = 0.125f * 1.44269504f;  // scale^2 * log2(e)
  const u16* kb0 = k_cl + (size_t)bh * TT * HCH;
  const u16* vb0 = v_cm + (size_t)bh * HCH * TT;
  for (int st = 0; st < 16; st++) {
    int s0 = st * 64;
#pragma unroll
    for (int r = 0; r < 2; r++) {
      int chunk = tid + r * 256;
      int row = chunk >> 3;
      int slot = (chunk & 7) ^ (row & 7);
      gld_lds16((const char*)(kb0 + ((size_t)(s0 + row)) * HCH) + slot * 16, Ks + chunk * 16);
      gld_lds16((const char*)(vb0 + (size_t)row * TT + s0) + slot * 16, Vs + chunk * 16);
    }
    __syncthreads();
    f32x4 sacc[2][4] = {};
    bf16x8 kf[4][2];
#pragma unroll
    for (int sb = 0; sb < 4; sb++)
#pragma unroll
      for (int ks = 0; ks < 2; ks++) {
        int row = sb * 16 + r15;
        int slot = (ks * 4 + g) ^ (row & 7);
        kf[sb][ks] = *(const bf16x8*)(Ks + row * 128 + slot * 16);
      }
#pragma unroll
    for (int tb = 0; tb < 2; tb++)
#pragma unroll
      for (int sb = 0; sb < 4; sb++)
#pragma unroll
        for (int ks = 0; ks < 2; ks++)
          sacc[tb][sb] = __builtin_amdgcn_mfma_f32_16x16x32_bf16(qf[tb][ks], kf[sb][ks], sacc[tb][sb], 0, 0, 0);
    // online softmax in base-2 domain; reuse sacc as P
#pragma unroll
    for (int tb = 0; tb < 2; tb++) {
      float corr[4];
#pragma unroll
      for (int r = 0; r < 4; r++) {
        float z0 = sacc[tb][0][r] * SC, z1 = sacc[tb][1][r] * SC;
        float z2 = sacc[tb][2][r] * SC, z3 = sacc[tb][3][r] * SC;
        float mx = fmaxf(fmaxf(z0, z1), fmaxf(z2, z3));
        mx = fmaxf(mx, __shfl_xor(mx, 1));
        mx = fmaxf(mx, __shfl_xor(mx, 2));
        mx = fmaxf(mx, __shfl_xor(mx, 4));
        mx = fmaxf(mx, __shfl_xor(mx, 8));
        float mnew = fmaxf(mrow[tb][r], mx);
        float c = exp2f(mrow[tb][r] - mnew);
        mrow[tb][r] = mnew;
        corr[r] = c;
        float e0 = exp2f(z0 - mnew), e1 = exp2f(z1 - mnew);
        float e2 = exp2f(z2 - mnew), e3 = exp2f(z3 - mnew);
        sacc[tb][0][r] = e0; sacc[tb][1][r] = e1;
        sacc[tb][2][r] = e2; sacc[tb][3][r] = e3;
        float ps = e0 + e1 + e2 + e3;
        ps += __shfl_xor(ps, 1); ps += __shfl_xor(ps, 2);
        ps += __shfl_xor(ps, 4); ps += __shfl_xor(ps, 8);
        lrow[tb][r] = lrow[tb][r] * c + ps;
      }
#pragma unroll
      for (int cb = 0; cb < 4; cb++)
#pragma unroll
        for (int r = 0; r < 4; r++) oacc[tb][cb][r] *= corr[r];
    }
    // P -> LDS (bf16), per-wave private region, swizzled rows of 128B
#pragma unroll
    for (int tb = 0; tb < 2; tb++)
#pragma unroll
      for (int sb = 0; sb < 4; sb++) {
        int s = sb * 16 + r15;
        int sl = s >> 3;
#pragma unroll
        for (int r = 0; r < 4; r++) {
          int tr = tb * 16 + g * 4 + r;
          int byte = tr * 128 + ((sl ^ (tr & 7)) * 16) + (s & 7) * 2;
          *(u16*)(Pw + byte) = f2bf(sacc[tb][sb][r]);
        }
      }
    // PV
    bf16x8 pf[2][2];
#pragma unroll
    for (int tb = 0; tb < 2; tb++)
#pragma unroll
      for (int ks = 0; ks < 2; ks++) {
        int row = tb * 16 + r15;
        int slot = (ks * 4 + g) ^ (row & 7);
        pf[tb][ks] = *(const bf16x8*)(Pw + row * 128 + slot * 16);
      }
    bf16x8 vf[4][2];
#pragma unroll
    for (int cb = 0; cb < 4; cb++)
#pragma unroll
      for (int ks = 0; ks < 2; ks++) {
        int row = cb * 16 + r15;
        int slot = (ks * 4 + g) ^ (row & 7);
        vf[cb][ks] = *(const bf16x8*)(Vs + row * 128 + slot * 16);
      }
#pragma unroll
    for (int tb = 0; tb < 2; tb++)
#pragma unroll
      for (int cb = 0; cb < 4; cb++)
#pragma unroll
        for (int ks = 0; ks < 2; ks++)
          oacc[tb][cb] = __builtin_amdgcn_mfma_f32_16x16x32_bf16(pf[tb][ks], vf[cb][ks], oacc[tb][cb], 0, 0, 0);
    __syncthreads();
  }
  // write a, channels-last full [b*T+t][512]
  int b = bh >> 3, h = bh & 7;
#pragma unroll
  for (int tb = 0; tb < 2; tb++)
#pragma unroll
    for (int r = 0; r < 4; r++) {
      float inv = 1.0f / lrow[tb][r];
      int t = t0 + wid * 32 + tb * 16 + g * 4 + r;
      u16* dst = a_cl + ((size_t)(b * TT + t)) * CH + h * HCH;
#pragma unroll
      for (int cb = 0; cb < 4; cb++)
        dst[cb * 16 + r15] = f2bf(oacc[tb][cb][r] * inv);
    }
}

// ---------------- launcher ----------------
extern "C" void kernel_launch(void* const* d_in, const int* in_sizes, int n_in,
                              void* d_out, int out_size, void* d_ws, size_t ws_size,
                              hipStream_t stream) {
  const float* x = (const float*)d_in[0];
  const float* gamma = (const float*)d_in[1];
  const float* beta = (const float*)d_in[2];
  const float* w_qkv = (const float*)d_in[3];
  const float* b_qkv = (const float*)d_in[4];
  const float* w_proj = (const float*)d_in[5];
  const float* b_proj = (const float*)d_in[6];
  float* out = (float*)d_out;
  char* ws = (char*)d_ws;
  u16* wqb = (u16*)ws;                      // 1.5 MB
  u16* wpb = (u16*)(ws + 0x180000);         // 0.5 MB
  u16* xn  = (u16*)(ws + 0x200000);         // 16 MB (reused as a_cl)
  u16* qcl = (u16*)(ws + 0x1200000);        // 16 MB
  u16* kcl = (u16*)(ws + 0x2200000);        // 16 MB
  u16* vcm = (u16*)(ws + 0x3200000);        // 16 MB
  hipLaunchKernelGGL(castw_kernel, dim3(3072), dim3(256), 0, stream, w_qkv, w_proj, wqb, wpb);
  hipLaunchKernelGGL(gn_kernel, dim3(512), dim3(256), 0, stream, x, gamma, beta, xn);
  hipLaunchKernelGGL(gemm_kernel<0>, dim3(12 * 128), dim3(256), 0, stream,
                     wqb, xn, b_qkv, (const float*)nullptr,
                     qcl, kcl, vcm, (float*)nullptr, 12);
  hipLaunchKernelGGL(attn_kernel, dim3(1024), dim3(256), 0, stream, qcl, kcl, vcm, xn);
  hipLaunchKernelGGL(gemm_kernel<1>, dim3(4 * 128), dim3(256), 0, stream,
                     wpb, xn, b_proj, x,
                     (u16*)nullptr, (u16*)nullptr, (u16*)nullptr, out, 4);
}

// Round 4
// 318.100 us; speedup vs baseline: 1.1701x; 1.1701x over previous
//
#include <hip/hip_runtime.h>
#include <hip/hip_bf16.h>

#define CH 512
#define TT 1024
#define NH 8
#define HCH 64

typedef unsigned short u16;
typedef unsigned int u32;
typedef __attribute__((ext_vector_type(8))) __bf16 bf16x8;
typedef __attribute__((ext_vector_type(4))) float f32x4;

__device__ inline u16 f2bf(float x) {
  union { __hip_bfloat16 b; u16 u; } v; v.b = __float2bfloat16(x); return v.u;
}

#define AS1 __attribute__((address_space(1)))
#define AS3 __attribute__((address_space(3)))
__device__ inline void gld_lds16(const void* src, void* dst) {
  __builtin_amdgcn_global_load_lds((const AS1 u32*)src, (AS3 u32*)dst, 16, 0, 0);
}

// ---------------- weight cast fp32 -> bf16 ----------------
__global__ __launch_bounds__(256) void castw_kernel(
    const float* __restrict__ wq, const float* __restrict__ wp,
    u16* __restrict__ wqb, u16* __restrict__ wpb) {
  int i = blockIdx.x * 256 + threadIdx.x;
  if (i < 3 * CH * CH) wqb[i] = f2bf(wq[i]);
  if (i < CH * CH) wpb[i] = f2bf(wp[i]);
}

// ---------------- GroupNorm -> channels-last bf16 ----------------
__global__ __launch_bounds__(256) void gn_kernel(
    const float* __restrict__ x, const float* __restrict__ gamma,
    const float* __restrict__ beta, u16* __restrict__ xn) {
  int b = blockIdx.x >> 5, g = blockIdx.x & 31;
  const float* xp = x + ((size_t)(b * CH + g * 16)) * TT;
  int tid = threadIdx.x;
  float s = 0.f, s2 = 0.f;
  for (int i = tid; i < 16 * TT; i += 256) {
    float v = xp[i]; s += v; s2 += v * v;
  }
  for (int o = 32; o; o >>= 1) { s += __shfl_down(s, o); s2 += __shfl_down(s2, o); }
  __shared__ float red[8];
  int wid = tid >> 6;
  if ((tid & 63) == 0) { red[wid] = s; red[wid + 4] = s2; }
  __syncthreads();
  s = red[0] + red[1] + red[2] + red[3];
  s2 = red[4] + red[5] + red[6] + red[7];
  const float invN = 1.f / (16.f * TT);
  float mean = s * invN;
  float rstd = rsqrtf(fmaxf(s2 * invN - mean * mean, 0.f) + 1e-5f);
  float ga[16], be[16];
#pragma unroll
  for (int c = 0; c < 16; c++) {
    float gg = gamma[g * 16 + c] * rstd;
    ga[c] = gg; be[c] = beta[g * 16 + c] - mean * gg;
  }
  for (int t = tid; t < TT; t += 256) {
    union { u16 v[16]; uint4 q[2]; } pk;
#pragma unroll
    for (int c = 0; c < 16; c++) pk.v[c] = f2bf(xp[c * TT + t] * ga[c] + be[c]);
    u16* dst = xn + ((size_t)(b * TT + t)) * CH + g * 16;
    *(uint4*)dst = pk.q[0];
    *(uint4*)(dst + 8) = pk.q[1];
  }
}

// ---------------- GEMM helpers ----------------
// LDS tile: [128 rows][4 slots x 16B], swizzle slot ^= (row>>1)&3, rows stride CH elems in global
__device__ inline void stage512(const u16* grow0, char* ldsb, int tid) {
#pragma unroll
  for (int r = 0; r < 2; r++) {
    int chunk = tid + r * 256;
    int row = chunk >> 2;
    int slot = (chunk & 3) ^ ((row >> 1) & 3);
    gld_lds16((const char*)(grow0 + (size_t)row * CH) + slot * 16, ldsb + chunk * 16);
  }
}
__device__ inline bf16x8 frag512(const char* ldsb, int row, int g) {
  int slot = g ^ ((row >> 1) & 3);
  return *(const bf16x8*)(ldsb + row * 64 + slot * 16);
}

// EPI 0: qkv epilogue (scatter q/k channels-last per head, v channel-major)
// EPI 1: proj epilogue (residual + bias, fp32 out)
template <int EPI>
__global__ __launch_bounds__(256) void gemm_kernel(
    const u16* __restrict__ A, const u16* __restrict__ B,
    const float* __restrict__ bias, const float* __restrict__ xres,
    u16* __restrict__ q_cl, u16* __restrict__ k_cl, u16* __restrict__ v_cm,
    float* __restrict__ outp, int Mtiles) {
  __shared__ char lds[32768];
  int tid = threadIdx.x;
  int mt = blockIdx.x % Mtiles, nt = blockIdx.x / Mtiles;
  const u16* Ab = A + (size_t)mt * 128 * CH;
  const u16* Bb = B + (size_t)nt * 128 * CH;
  int lane = tid & 63, wid = tid >> 6;
  int g = lane >> 4, r15 = lane & 15;
  int wrow = (wid >> 1) * 64, wcol = (wid & 1) * 64;
  f32x4 acc[4][4] = {};
  stage512(Ab, lds, tid);
  stage512(Bb, lds + 8192, tid);
  __syncthreads();
  for (int kt = 0; kt < CH / 32; kt++) {
    int cur = kt & 1;
    char* Ac = lds + cur * 16384;
    char* Bc = lds + 8192 + cur * 16384;
    if (kt + 1 < CH / 32) {
      char* An = lds + (cur ^ 1) * 16384;
      stage512(Ab + (kt + 1) * 32, An, tid);
      stage512(Bb + (kt + 1) * 32, An + 8192, tid);
    }
    bf16x8 af[4], bfr[4];
#pragma unroll
    for (int i = 0; i < 4; i++) af[i] = frag512(Ac, wrow + i * 16 + r15, g);
#pragma unroll
    for (int j = 0; j < 4; j++) bfr[j] = frag512(Bc, wcol + j * 16 + r15, g);
#pragma unroll
    for (int i = 0; i < 4; i++)
#pragma unroll
      for (int j = 0; j < 4; j++)
        acc[i][j] = __builtin_amdgcn_mfma_f32_16x16x32_bf16(af[i], bfr[j], acc[i][j], 0, 0, 0);
    __syncthreads();
  }
  int m0 = mt * 128 + wrow;
  if (EPI == 0) {
    int type = (m0 >> 6) % 3;
    int h = m0 / 192;
#pragma unroll
    for (int i = 0; i < 4; i++) {
      float bv[4];
#pragma unroll
      for (int r = 0; r < 4; r++) bv[r] = bias[m0 + i * 16 + g * 4 + r];
#pragma unroll
      for (int j = 0; j < 4; j++) {
        int n = nt * 128 + wcol + j * 16 + r15;
        int t = n & (TT - 1);
        int bh = (n >> 10) * NH + h;
        if (type == 2) {
#pragma unroll
          for (int r = 0; r < 4; r++) {
            int cp = i * 16 + g * 4 + r;
            v_cm[((size_t)bh * HCH + cp) * TT + t] = f2bf(acc[i][j][r] + bv[r]);
          }
        } else {
          union { u16 v[4]; uint2 u; } pk;
#pragma unroll
          for (int r = 0; r < 4; r++) pk.v[r] = f2bf(acc[i][j][r] + bv[r]);
          u16* dst = (type == 0 ? q_cl : k_cl) + ((size_t)bh * TT + t) * HCH + i * 16 + g * 4;
          *(uint2*)dst = pk.u;
        }
      }
    }
  } else {
#pragma unroll
    for (int i = 0; i < 4; i++) {
      float bv[4];
#pragma unroll
      for (int r = 0; r < 4; r++) bv[r] = bias[m0 + i * 16 + g * 4 + r];
#pragma unroll
      for (int j = 0; j < 4; j++) {
        int n = nt * 128 + wcol + j * 16 + r15;
        int t = n & (TT - 1);
        int bb = n >> 10;
#pragma unroll
        for (int r = 0; r < 4; r++) {
          size_t oi = ((size_t)bb * CH + m0 + i * 16 + g * 4 + r) * TT + t;
          outp[oi] = xres[oi] + acc[i][j][r] + bv[r];
        }
      }
    }
  }
}

// ---------------- flash attention (2-phase K/V double-buffer, Q in regs, defer-max) ----------------
// LDS 48KB: K dbuf [2][8KB] @0, V dbuf [2][8KB] @16384, P per-wave 4KB @32768
__device__ inline void stageKV(const u16* kb, const u16* vb, int s0,
                               char* Kd, char* Vd, int tid) {
#pragma unroll
  for (int r = 0; r < 2; r++) {
    int chunk = tid + r * 256;
    int row = chunk >> 3;
    int slot = (chunk & 7) ^ (row & 7);
    gld_lds16((const char*)(kb + (size_t)(s0 + row) * HCH) + slot * 16, Kd + chunk * 16);
    gld_lds16((const char*)(vb + (size_t)row * TT + s0) + slot * 16, Vd + chunk * 16);
  }
}

__global__ __launch_bounds__(256) void attn_kernel(
    const u16* __restrict__ q_cl, const u16* __restrict__ k_cl,
    const u16* __restrict__ v_cm, u16* __restrict__ a_cl) {
  int bh = blockIdx.x >> 3;
  int t0 = (blockIdx.x & 7) * 128;
  __shared__ char lds[49152];
  int tid = threadIdx.x, lane = tid & 63, wid = tid >> 6;
  int g = lane >> 4, r15 = lane & 15;
  const u16* kb0 = k_cl + (size_t)bh * TT * HCH;
  const u16* vb0 = v_cm + (size_t)bh * HCH * TT;
  // prefetch tile 0 into buf 0
  stageKV(kb0, vb0, 0, lds, lds + 16384, tid);
  // Q direct global -> registers (row = t, 16B per (ks,g) chunk)
  const u16* qb = q_cl + ((size_t)(bh * TT + t0)) * HCH;
  bf16x8 qf[2][2];
#pragma unroll
  for (int tb = 0; tb < 2; tb++)
#pragma unroll
    for (int ks = 0; ks < 2; ks++)
      qf[tb][ks] = *(const bf16x8*)(qb + (size_t)(wid * 32 + tb * 16 + r15) * HCH + ks * 32 + g * 8);
  __syncthreads();  // drains stage(0) + q loads
  f32x4 oacc[2][4] = {};
  float mrow[2][4], lrow[2][4];
#pragma unroll
  for (int tb = 0; tb < 2; tb++)
#pragma unroll
    for (int r = 0; r < 4; r++) { mrow[tb][r] = -3.0e38f; lrow[tb][r] = 0.f; }
  char* Pw = lds + 32768 + wid * 4096;
  const float SC = 0.125f * 1.44269504f;  // scale^2 * log2(e)
  for (int st = 0; st < 16; st++) {
    char* Kc = lds + (st & 1) * 8192;
    char* Vc = lds + 16384 + (st & 1) * 8192;
    // prefetch next tile into the other buffer (overlaps with this tile's compute)
    if (st + 1 < 16)
      stageKV(kb0, vb0, (st + 1) * 64,
              lds + ((st + 1) & 1) * 8192, lds + 16384 + ((st + 1) & 1) * 8192, tid);
    // QK^T
    f32x4 sacc[2][4] = {};
    bf16x8 kf[4][2];
#pragma unroll
    for (int sb = 0; sb < 4; sb++)
#pragma unroll
      for (int ks = 0; ks < 2; ks++) {
        int row = sb * 16 + r15;
        int slot = (ks * 4 + g) ^ (row & 7);
        kf[sb][ks] = *(const bf16x8*)(Kc + row * 128 + slot * 16);
      }
#pragma unroll
    for (int tb = 0; tb < 2; tb++)
#pragma unroll
      for (int sb = 0; sb < 4; sb++)
#pragma unroll
        for (int ks = 0; ks < 2; ks++)
          sacc[tb][sb] = __builtin_amdgcn_mfma_f32_16x16x32_bf16(qf[tb][ks], kf[sb][ks], sacc[tb][sb], 0, 0, 0);
    // scale + row max (reduced over 16 lanes), defer-max decision
    float mx[2][4];
    bool keep = true;
#pragma unroll
    for (int tb = 0; tb < 2; tb++)
#pragma unroll
      for (int r = 0; r < 4; r++) {
        float z0 = sacc[tb][0][r] * SC, z1 = sacc[tb][1][r] * SC;
        float z2 = sacc[tb][2][r] * SC, z3 = sacc[tb][3][r] * SC;
        sacc[tb][0][r] = z0; sacc[tb][1][r] = z1;
        sacc[tb][2][r] = z2; sacc[tb][3][r] = z3;
        float m = fmaxf(fmaxf(z0, z1), fmaxf(z2, z3));
        m = fmaxf(m, __shfl_xor(m, 1));
        m = fmaxf(m, __shfl_xor(m, 2));
        m = fmaxf(m, __shfl_xor(m, 4));
        m = fmaxf(m, __shfl_xor(m, 8));
        mx[tb][r] = m;
        keep = keep && (m <= mrow[tb][r] + 8.0f);
      }
    if (!__all(keep)) {
#pragma unroll
      for (int tb = 0; tb < 2; tb++)
#pragma unroll
        for (int r = 0; r < 4; r++) {
          float mnew = fmaxf(mrow[tb][r], mx[tb][r]);
          float c = exp2f(mrow[tb][r] - mnew);
          mrow[tb][r] = mnew;
          lrow[tb][r] *= c;
#pragma unroll
          for (int cb = 0; cb < 4; cb++) oacc[tb][cb][r] *= c;
        }
    }
    // exponentiate + row sum
#pragma unroll
    for (int tb = 0; tb < 2; tb++)
#pragma unroll
      for (int r = 0; r < 4; r++) {
        float mr = mrow[tb][r];
        float e0 = exp2f(sacc[tb][0][r] - mr), e1 = exp2f(sacc[tb][1][r] - mr);
        float e2 = exp2f(sacc[tb][2][r] - mr), e3 = exp2f(sacc[tb][3][r] - mr);
        sacc[tb][0][r] = e0; sacc[tb][1][r] = e1;
        sacc[tb][2][r] = e2; sacc[tb][3][r] = e3;
        float ps = e0 + e1 + e2 + e3;
        ps += __shfl_xor(ps, 1); ps += __shfl_xor(ps, 2);
        ps += __shfl_xor(ps, 4); ps += __shfl_xor(ps, 8);
        lrow[tb][r] += ps;
      }
    // P -> LDS (bf16), per-wave private region, swizzled rows of 128B
#pragma unroll
    for (int tb = 0; tb < 2; tb++)
#pragma unroll
      for (int sb = 0; sb < 4; sb++) {
        int s = sb * 16 + r15;
        int sl = s >> 3;
#pragma unroll
        for (int r = 0; r < 4; r++) {
          int tr = tb * 16 + g * 4 + r;
          int byte = tr * 128 + ((sl ^ (tr & 7)) * 16) + (s & 7) * 2;
          *(u16*)(Pw + byte) = f2bf(sacc[tb][sb][r]);
        }
      }
    // PV
    bf16x8 pf[2][2];
#pragma unroll
    for (int tb = 0; tb < 2; tb++)
#pragma unroll
      for (int ks = 0; ks < 2; ks++) {
        int row = tb * 16 + r15;
        int slot = (ks * 4 + g) ^ (row & 7);
        pf[tb][ks] = *(const bf16x8*)(Pw + row * 128 + slot * 16);
      }
    bf16x8 vf[4][2];
#pragma unroll
    for (int cb = 0; cb < 4; cb++)
#pragma unroll
      for (int ks = 0; ks < 2; ks++) {
        int row = cb * 16 + r15;
        int slot = (ks * 4 + g) ^ (row & 7);
        vf[cb][ks] = *(const bf16x8*)(Vc + row * 128 + slot * 16);
      }
#pragma unroll
    for (int tb = 0; tb < 2; tb++)
#pragma unroll
      for (int cb = 0; cb < 4; cb++)
#pragma unroll
        for (int ks = 0; ks < 2; ks++)
          oacc[tb][cb] = __builtin_amdgcn_mfma_f32_16x16x32_bf16(pf[tb][ks], vf[cb][ks], oacc[tb][cb], 0, 0, 0);
    // one barrier per tile: waits this tile's LDS reads + next tile's prefetch
    __syncthreads();
  }
  // write a, channels-last full [b*T+t][512]
  int b = bh >> 3, h = bh & 7;
#pragma unroll
  for (int tb = 0; tb < 2; tb++)
#pragma unroll
    for (int r = 0; r < 4; r++) {
      float inv = 1.0f / lrow[tb][r];
      int t = t0 + wid * 32 + tb * 16 + g * 4 + r;
      u16* dst = a_cl + ((size_t)(b * TT + t)) * CH + h * HCH;
#pragma unroll
      for (int cb = 0; cb < 4; cb++)
        dst[cb * 16 + r15] = f2bf(oacc[tb][cb][r] * inv);
    }
}

// ---------------- launcher ----------------
extern "C" void kernel_launch(void* const* d_in, const int* in_sizes, int n_in,
                              void* d_out, int out_size, void* d_ws, size_t ws_size,
                              hipStream_t stream) {
  const float* x = (const float*)d_in[0];
  const float* gamma = (const float*)d_in[1];
  const float* beta = (const float*)d_in[2];
  const float* w_qkv = (const float*)d_in[3];
  const float* b_qkv = (const float*)d_in[4];
  const float* w_proj = (const float*)d_in[5];
  const float* b_proj = (const float*)d_in[6];
  float* out = (float*)d_out;
  char* ws = (char*)d_ws;
  u16* wqb = (u16*)ws;                      // 1.5 MB
  u16* wpb = (u16*)(ws + 0x180000);         // 0.5 MB
  u16* xn  = (u16*)(ws + 0x200000);         // 16 MB (reused as a_cl)
  u16* qcl = (u16*)(ws + 0x1200000);        // 16 MB
  u16* kcl = (u16*)(ws + 0x2200000);        // 16 MB
  u16* vcm = (u16*)(ws + 0x3200000);        // 16 MB
  hipLaunchKernelGGL(castw_kernel, dim3(3072), dim3(256), 0, stream, w_qkv, w_proj, wqb, wpb);
  hipLaunchKernelGGL(gn_kernel, dim3(512), dim3(256), 0, stream, x, gamma, beta, xn);
  hipLaunchKernelGGL(gemm_kernel<0>, dim3(12 * 128), dim3(256), 0, stream,
                     wqb, xn, b_qkv, (const float*)nullptr,
                     qcl, kcl, vcm, (float*)nullptr, 12);
  hipLaunchKernelGGL(attn_kernel, dim3(1024), dim3(256), 0, stream, qcl, kcl, vcm, xn);
  hipLaunchKernelGGL(gemm_kernel<1>, dim3(4 * 128), dim3(256), 0, stream,
                     wpb, xn, b_proj, x,
                     (u16*)nullptr, (u16*)nullptr, (u16*)nullptr, out, 4);
}

// Round 6
// 276.443 us; speedup vs baseline: 1.3464x; 1.1507x over previous
//
#include <hip/hip_runtime.h>
#include <hip/hip_bf16.h>

#define CH 512
#define TT 1024
#define NH 8
#define HCH 64

typedef unsigned short u16;
typedef unsigned int u32;
typedef __attribute__((ext_vector_type(8))) __bf16 bf16x8;
typedef __attribute__((ext_vector_type(4))) float f32x4;

__device__ inline u16 f2bf(float x) {
  union { __hip_bfloat16 b; u16 u; } v; v.b = __float2bfloat16(x); return v.u;
}
__device__ inline float max4(f32x4 v) {
  return fmaxf(fmaxf(v[0], v[1]), fmaxf(v[2], v[3]));
}

#define AS1 __attribute__((address_space(1)))
#define AS3 __attribute__((address_space(3)))
__device__ inline void gld_lds16(const void* src, void* dst) {
  __builtin_amdgcn_global_load_lds((const AS1 u32*)src, (AS3 u32*)dst, 16, 0, 0);
}

// ---------------- weight cast fp32 -> bf16 ----------------
__global__ __launch_bounds__(256) void castw_kernel(
    const float* __restrict__ wq, const float* __restrict__ wp,
    u16* __restrict__ wqb, u16* __restrict__ wpb) {
  int i = blockIdx.x * 256 + threadIdx.x;
  if (i < 3 * CH * CH) wqb[i] = f2bf(wq[i]);
  if (i < CH * CH) wpb[i] = f2bf(wp[i]);
}

// ---------------- GroupNorm -> channels-last bf16 ----------------
__global__ __launch_bounds__(256) void gn_kernel(
    const float* __restrict__ x, const float* __restrict__ gamma,
    const float* __restrict__ beta, u16* __restrict__ xn) {
  int b = blockIdx.x >> 5, g = blockIdx.x & 31;
  const float* xp = x + ((size_t)(b * CH + g * 16)) * TT;
  int tid = threadIdx.x;
  float s = 0.f, s2 = 0.f;
  for (int i = tid; i < 16 * TT; i += 256) {
    float v = xp[i]; s += v; s2 += v * v;
  }
  for (int o = 32; o; o >>= 1) { s += __shfl_down(s, o); s2 += __shfl_down(s2, o); }
  __shared__ float red[8];
  int wid = tid >> 6;
  if ((tid & 63) == 0) { red[wid] = s; red[wid + 4] = s2; }
  __syncthreads();
  s = red[0] + red[1] + red[2] + red[3];
  s2 = red[4] + red[5] + red[6] + red[7];
  const float invN = 1.f / (16.f * TT);
  float mean = s * invN;
  float rstd = rsqrtf(fmaxf(s2 * invN - mean * mean, 0.f) + 1e-5f);
  float ga[16], be[16];
#pragma unroll
  for (int c = 0; c < 16; c++) {
    float gg = gamma[g * 16 + c] * rstd;
    ga[c] = gg; be[c] = beta[g * 16 + c] - mean * gg;
  }
  for (int t = tid; t < TT; t += 256) {
    union { u16 v[16]; uint4 q[2]; } pk;
#pragma unroll
    for (int c = 0; c < 16; c++) pk.v[c] = f2bf(xp[c * TT + t] * ga[c] + be[c]);
    u16* dst = xn + ((size_t)(b * TT + t)) * CH + g * 16;
    *(uint4*)dst = pk.q[0];
    *(uint4*)(dst + 8) = pk.q[1];
  }
}

// ---------------- GEMM helpers ----------------
// LDS tile: [128 rows][4 slots x 16B], swizzle slot ^= (row>>1)&3, rows stride CH elems in global
__device__ inline void stage512(const u16* grow0, char* ldsb, int tid) {
#pragma unroll
  for (int r = 0; r < 2; r++) {
    int chunk = tid + r * 256;
    int row = chunk >> 2;
    int slot = (chunk & 3) ^ ((row >> 1) & 3);
    gld_lds16((const char*)(grow0 + (size_t)row * CH) + slot * 16, ldsb + chunk * 16);
  }
}
__device__ inline bf16x8 frag512(const char* ldsb, int row, int g) {
  int slot = g ^ ((row >> 1) & 3);
  return *(const bf16x8*)(ldsb + row * 64 + slot * 16);
}

// EPI 0: qkv epilogue (scatter q/k channels-last per head, v channel-major)
// EPI 1: proj epilogue (residual + bias, fp32 out)
template <int EPI>
__global__ __launch_bounds__(256) void gemm_kernel(
    const u16* __restrict__ A, const u16* __restrict__ B,
    const float* __restrict__ bias, const float* __restrict__ xres,
    u16* __restrict__ q_cl, u16* __restrict__ k_cl, u16* __restrict__ v_cm,
    float* __restrict__ outp, int Mtiles) {
  __shared__ char lds[32768];
  int tid = threadIdx.x;
  int mt = blockIdx.x % Mtiles, nt = blockIdx.x / Mtiles;
  const u16* Ab = A + (size_t)mt * 128 * CH;
  const u16* Bb = B + (size_t)nt * 128 * CH;
  int lane = tid & 63, wid = tid >> 6;
  int g = lane >> 4, r15 = lane & 15;
  int wrow = (wid >> 1) * 64, wcol = (wid & 1) * 64;
  f32x4 acc[4][4] = {};
  stage512(Ab, lds, tid);
  stage512(Bb, lds + 8192, tid);
  __syncthreads();
  for (int kt = 0; kt < CH / 32; kt++) {
    int cur = kt & 1;
    char* Ac = lds + cur * 16384;
    char* Bc = lds + 8192 + cur * 16384;
    if (kt + 1 < CH / 32) {
      char* An = lds + (cur ^ 1) * 16384;
      stage512(Ab + (kt + 1) * 32, An, tid);
      stage512(Bb + (kt + 1) * 32, An + 8192, tid);
    }
    bf16x8 af[4], bfr[4];
#pragma unroll
    for (int i = 0; i < 4; i++) af[i] = frag512(Ac, wrow + i * 16 + r15, g);
#pragma unroll
    for (int j = 0; j < 4; j++) bfr[j] = frag512(Bc, wcol + j * 16 + r15, g);
#pragma unroll
    for (int i = 0; i < 4; i++)
#pragma unroll
      for (int j = 0; j < 4; j++)
        acc[i][j] = __builtin_amdgcn_mfma_f32_16x16x32_bf16(af[i], bfr[j], acc[i][j], 0, 0, 0);
    __syncthreads();
  }
  int m0 = mt * 128 + wrow;
  if (EPI == 0) {
    int type = (m0 >> 6) % 3;
    int h = m0 / 192;
#pragma unroll
    for (int i = 0; i < 4; i++) {
      float bv[4];
#pragma unroll
      for (int r = 0; r < 4; r++) bv[r] = bias[m0 + i * 16 + g * 4 + r];
#pragma unroll
      for (int j = 0; j < 4; j++) {
        int n = nt * 128 + wcol + j * 16 + r15;
        int t = n & (TT - 1);
        int bh = (n >> 10) * NH + h;
        if (type == 2) {
#pragma unroll
          for (int r = 0; r < 4; r++) {
            int cp = i * 16 + g * 4 + r;
            v_cm[((size_t)bh * HCH + cp) * TT + t] = f2bf(acc[i][j][r] + bv[r]);
          }
        } else {
          union { u16 v[4]; uint2 u; } pk;
#pragma unroll
          for (int r = 0; r < 4; r++) pk.v[r] = f2bf(acc[i][j][r] + bv[r]);
          u16* dst = (type == 0 ? q_cl : k_cl) + ((size_t)bh * TT + t) * HCH + i * 16 + g * 4;
          *(uint2*)dst = pk.u;
        }
      }
    }
  } else {
#pragma unroll
    for (int i = 0; i < 4; i++) {
      float bv[4];
#pragma unroll
      for (int r = 0; r < 4; r++) bv[r] = bias[m0 + i * 16 + g * 4 + r];
#pragma unroll
      for (int j = 0; j < 4; j++) {
        int n = nt * 128 + wcol + j * 16 + r15;
        int t = n & (TT - 1);
        int bb = n >> 10;
#pragma unroll
        for (int r = 0; r < 4; r++) {
          size_t oi = ((size_t)bb * CH + m0 + i * 16 + g * 4 + r) * TT + t;
          outp[oi] = xres[oi] + acc[i][j][r] + bv[r];
        }
      }
    }
  }
}

// ---------------- flash attention ----------------
// Swapped QK^T (mfma(K,Q)) => lane holds P[s=sb*16+g*4+r][t=r15]: softmax row is
// lane-local (15 max ops + 2 shfl_xor); P-fragment for PV built fully in-register
// using the k-slot bijection s(g,j) = ks*32 + (j>>2)*16 + g*4 + (j&3), with V read
// under the same bijection as two ds_read_b64 from the swizzled V tile.
// LDS 32KB: K dbuf [2][8KB] @0, V dbuf [2][8KB] @16384.
__device__ inline void stageKV(const u16* kb, const u16* vb, int s0,
                               char* Kd, char* Vd, int tid) {
#pragma unroll
  for (int r = 0; r < 2; r++) {
    int chunk = tid + r * 256;
    int row = chunk >> 3;
    int slot = (chunk & 7) ^ (row & 7);
    gld_lds16((const char*)(kb + (size_t)(s0 + row) * HCH) + slot * 16, Kd + chunk * 16);
    gld_lds16((const char*)(vb + (size_t)row * TT + s0) + slot * 16, Vd + chunk * 16);
  }
}

__global__ __launch_bounds__(256) void attn_kernel(
    const u16* __restrict__ q_cl, const u16* __restrict__ k_cl,
    const u16* __restrict__ v_cm, u16* __restrict__ a_cl) {
  int bh = blockIdx.x >> 3;
  int t0 = (blockIdx.x & 7) * 128;
  __shared__ char lds[32768];
  int tid = threadIdx.x, lane = tid & 63, wid = tid >> 6;
  int g = lane >> 4, r15 = lane & 15;
  int tbase = (lane & 48) | ((lane & 48) >> 2);  // shfl src base: lane with r15 = g*4 (+r)
  const u16* kb0 = k_cl + (size_t)bh * TT * HCH;
  const u16* vb0 = v_cm + (size_t)bh * HCH * TT;
  // prefetch tile 0 into buf 0
  stageKV(kb0, vb0, 0, lds, lds + 16384, tid);
  // Q direct global -> registers (t = wid*32 + tb*16 + r15; d-chunk ks*32 + g*8)
  const u16* qb = q_cl + ((size_t)(bh * TT + t0)) * HCH;
  bf16x8 qf[2][2];
#pragma unroll
  for (int tb = 0; tb < 2; tb++)
#pragma unroll
    for (int ks = 0; ks < 2; ks++)
      qf[tb][ks] = *(const bf16x8*)(qb + (size_t)(wid * 32 + tb * 16 + r15) * HCH + ks * 32 + g * 8);
  __syncthreads();  // drains stage(0) + q loads
  f32x4 oacc[2][4] = {};
  float mrow[2] = {-3.0e38f, -3.0e38f};  // scaled-domain running max for t = r15 (+tb*16)
  float lrow[2] = {0.f, 0.f};
  const float SC = 0.125f * 1.44269504f;  // scale^2 * log2(e)
  for (int st = 0; st < 16; st++) {
    char* Kc = lds + (st & 1) * 8192;
    char* Vc = lds + 16384 + (st & 1) * 8192;
    if (st + 1 < 16)
      stageKV(kb0, vb0, (st + 1) * 64,
              lds + ((st + 1) & 1) * 8192, lds + 16384 + ((st + 1) & 1) * 8192, tid);
    // QK^T swapped: sacc[tb][sb] = S[s = sb*16 + g*4 + r][t = tb*16 + r15]
    f32x4 sacc[2][4] = {};
#pragma unroll
    for (int sb = 0; sb < 4; sb++) {
      int row = sb * 16 + r15;
      int sw = row & 7;
      bf16x8 k0 = *(const bf16x8*)(Kc + row * 128 + ((0 + g) ^ sw) * 16);
      bf16x8 k1 = *(const bf16x8*)(Kc + row * 128 + ((4 + g) ^ sw) * 16);
#pragma unroll
      for (int tb = 0; tb < 2; tb++) {
        sacc[tb][sb] = __builtin_amdgcn_mfma_f32_16x16x32_bf16(k0, qf[tb][0], sacc[tb][sb], 0, 0, 0);
        sacc[tb][sb] = __builtin_amdgcn_mfma_f32_16x16x32_bf16(k1, qf[tb][1], sacc[tb][sb], 0, 0, 0);
      }
    }
    // row max over this tile (raw domain; SC>0 so monotone), then defer-max check
    float mxs[2];
    bool keep = true;
#pragma unroll
    for (int tb = 0; tb < 2; tb++) {
      float m = fmaxf(fmaxf(max4(sacc[tb][0]), max4(sacc[tb][1])),
                      fmaxf(max4(sacc[tb][2]), max4(sacc[tb][3])));
      m = fmaxf(m, __shfl_xor(m, 16));
      m = fmaxf(m, __shfl_xor(m, 32));
      mxs[tb] = m * SC;
      keep = keep && (mxs[tb] <= mrow[tb] + 8.0f);
    }
    if (!__all(keep)) {
#pragma unroll
      for (int tb = 0; tb < 2; tb++) {
        float mnew = fmaxf(mrow[tb], mxs[tb]);
        float c = exp2f(mrow[tb] - mnew);
        mrow[tb] = mnew;
        lrow[tb] *= c;
#pragma unroll
        for (int r = 0; r < 4; r++) {
          float cr = __shfl(c, tbase + r);  // c for output row t-local = g*4+r
#pragma unroll
          for (int cb = 0; cb < 4; cb++) oacc[tb][cb][r] *= cr;
        }
      }
    }
    // exponentiate (fold scale into fma) + row sum; P kept in registers
    bf16x8 pf[2][2];
#pragma unroll
    for (int tb = 0; tb < 2; tb++) {
      float nm = -mrow[tb];
      float ps = 0.f;
#pragma unroll
      for (int sb = 0; sb < 4; sb++)
#pragma unroll
        for (int r = 0; r < 4; r++) {
          float e = exp2f(fmaf(sacc[tb][sb][r], SC, nm));
          sacc[tb][sb][r] = e;
          ps += e;
        }
      ps += __shfl_xor(ps, 16);
      ps += __shfl_xor(ps, 32);
      lrow[tb] += ps;
      // assemble PV A-fragments: slot j of ks holds s = ks*32 + (j>>2)*16 + g*4 + (j&3)
#pragma unroll
      for (int ks = 0; ks < 2; ks++) {
        union { u32 w[4]; bf16x8 v; } pk;
        pk.w[0] = (u32)f2bf(sacc[tb][2 * ks][0]) | ((u32)f2bf(sacc[tb][2 * ks][1]) << 16);
        pk.w[1] = (u32)f2bf(sacc[tb][2 * ks][2]) | ((u32)f2bf(sacc[tb][2 * ks][3]) << 16);
        pk.w[2] = (u32)f2bf(sacc[tb][2 * ks + 1][0]) | ((u32)f2bf(sacc[tb][2 * ks + 1][1]) << 16);
        pk.w[3] = (u32)f2bf(sacc[tb][2 * ks + 1][2]) | ((u32)f2bf(sacc[tb][2 * ks + 1][3]) << 16);
        pf[tb][ks] = pk.v;
      }
    }
    // PV: V fragment under the same bijection = two b64 reads per (cb, ks)
#pragma unroll
    for (int cb = 0; cb < 4; cb++) {
      int row = cb * 16 + r15;
      int sw = row & 7;
      int half = (g & 1) * 8;
      int gh = g >> 1;
#pragma unroll
      for (int ks = 0; ks < 2; ks++) {
        union { uint2 u[2]; bf16x8 v; } vv;
        vv.u[0] = *(const uint2*)(Vc + row * 128 + ((ks * 4 + gh) ^ sw) * 16 + half);
        vv.u[1] = *(const uint2*)(Vc + row * 128 + ((ks * 4 + 2 + gh) ^ sw) * 16 + half);
#pragma unroll
        for (int tb = 0; tb < 2; tb++)
          oacc[tb][cb] = __builtin_amdgcn_mfma_f32_16x16x32_bf16(pf[tb][ks], vv.v, oacc[tb][cb], 0, 0, 0);
      }
    }
    __syncthreads();  // waits this tile's LDS reads + next tile's prefetch
  }
  // write a, channels-last full [b*T+t][512]
  int b = bh >> 3, h = bh & 7;
#pragma unroll
  for (int tb = 0; tb < 2; tb++) {
    float inv = 1.0f / lrow[tb];  // for t = tb*16 + r15
#pragma unroll
    for (int r = 0; r < 4; r++) {
      float invr = __shfl(inv, tbase + r);  // for output row t-local = g*4+r
      int t = t0 + wid * 32 + tb * 16 + g * 4 + r;
      u16* dst = a_cl + ((size_t)(b * TT + t)) * CH + h * HCH;
#pragma unroll
      for (int cb = 0; cb < 4; cb++)
        dst[cb * 16 + r15] = f2bf(oacc[tb][cb][r] * invr);
    }
  }
}

// ---------------- launcher ----------------
extern "C" void kernel_launch(void* const* d_in, const int* in_sizes, int n_in,
                              void* d_out, int out_size, void* d_ws, size_t ws_size,
                              hipStream_t stream) {
  const float* x = (const float*)d_in[0];
  const float* gamma = (const float*)d_in[1];
  const float* beta = (const float*)d_in[2];
  const float* w_qkv = (const float*)d_in[3];
  const float* b_qkv = (const float*)d_in[4];
  const float* w_proj = (const float*)d_in[5];
  const float* b_proj = (const float*)d_in[6];
  float* out = (float*)d_out;
  char* ws = (char*)d_ws;
  u16* wqb = (u16*)ws;                      // 1.5 MB
  u16* wpb = (u16*)(ws + 0x180000);         // 0.5 MB
  u16* xn  = (u16*)(ws + 0x200000);         // 16 MB (reused as a_cl)
  u16* qcl = (u16*)(ws + 0x1200000);        // 16 MB
  u16* kcl = (u16*)(ws + 0x2200000);        // 16 MB
  u16* vcm = (u16*)(ws + 0x3200000);        // 16 MB
  hipLaunchKernelGGL(castw_kernel, dim3(3072), dim3(256), 0, stream, w_qkv, w_proj, wqb, wpb);
  hipLaunchKernelGGL(gn_kernel, dim3(512), dim3(256), 0, stream, x, gamma, beta, xn);
  hipLaunchKernelGGL(gemm_kernel<0>, dim3(12 * 128), dim3(256), 0, stream,
                     wqb, xn, b_qkv, (const float*)nullptr,
                     qcl, kcl, vcm, (float*)nullptr, 12);
  hipLaunchKernelGGL(attn_kernel, dim3(1024), dim3(256), 0, stream, qcl, kcl, vcm, xn);
  hipLaunchKernelGGL(gemm_kernel<1>, dim3(4 * 128), dim3(256), 0, stream,
                     wpb, xn, b_proj, x,
                     (u16*)nullptr, (u16*)nullptr, (u16*)nullptr, out, 4);
}

// Round 8
// 266.677 us; speedup vs baseline: 1.3957x; 1.0366x over previous
//
#include <hip/hip_runtime.h>
#include <hip/hip_bf16.h>

#define CH 512
#define TT 1024
#define NH 8
#define HCH 64

typedef unsigned short u16;
typedef unsigned int u32;
typedef __attribute__((ext_vector_type(8))) __bf16 bf16x8;
typedef __attribute__((ext_vector_type(4))) float f32x4;

__device__ inline u16 f2bf(float x) {
  union { __hip_bfloat16 b; u16 u; } v; v.b = __float2bfloat16(x); return v.u;
}
__device__ inline float max4(f32x4 v) {
  return fmaxf(fmaxf(v[0], v[1]), fmaxf(v[2], v[3]));
}
// XCD-aware bijective swizzle (nwg % 8 == 0): contiguous logical chunk per XCD
__device__ inline int xcd_swz(int bid, int nwg) {
  return (bid & 7) * (nwg >> 3) + (bid >> 3);
}

#define AS1 __attribute__((address_space(1)))
#define AS3 __attribute__((address_space(3)))
__device__ inline void gld_lds16(const void* src, void* dst) {
  __builtin_amdgcn_global_load_lds((const AS1 u32*)src, (AS3 u32*)dst, 16, 0, 0);
}

// ---------------- weight cast fp32 -> bf16 ----------------
__global__ __launch_bounds__(256) void castw_kernel(
    const float* __restrict__ wq, const float* __restrict__ wp,
    u16* __restrict__ wqb, u16* __restrict__ wpb) {
  int i = blockIdx.x * 256 + threadIdx.x;
  if (i < 3 * CH * CH) wqb[i] = f2bf(wq[i]);
  if (i < CH * CH) wpb[i] = f2bf(wp[i]);
}

// ---------------- GroupNorm -> channels-last bf16 ----------------
__global__ __launch_bounds__(256) void gn_kernel(
    const float* __restrict__ x, const float* __restrict__ gamma,
    const float* __restrict__ beta, u16* __restrict__ xn) {
  int b = blockIdx.x >> 5, g = blockIdx.x & 31;
  const float* xp = x + ((size_t)(b * CH + g * 16)) * TT;
  int tid = threadIdx.x;
  float s = 0.f, s2 = 0.f;
  for (int i = tid; i < 16 * TT; i += 256) {
    float v = xp[i]; s += v; s2 += v * v;
  }
  for (int o = 32; o; o >>= 1) { s += __shfl_down(s, o); s2 += __shfl_down(s2, o); }
  __shared__ float red[8];
  int wid = tid >> 6;
  if ((tid & 63) == 0) { red[wid] = s; red[wid + 4] = s2; }
  __syncthreads();
  s = red[0] + red[1] + red[2] + red[3];
  s2 = red[4] + red[5] + red[6] + red[7];
  const float invN = 1.f / (16.f * TT);
  float mean = s * invN;
  float rstd = rsqrtf(fmaxf(s2 * invN - mean * mean, 0.f) + 1e-5f);
  float ga[16], be[16];
#pragma unroll
  for (int c = 0; c < 16; c++) {
    float gg = gamma[g * 16 + c] * rstd;
    ga[c] = gg; be[c] = beta[g * 16 + c] - mean * gg;
  }
  for (int t = tid; t < TT; t += 256) {
    union { u16 v[16]; uint4 q[2]; } pk;
#pragma unroll
    for (int c = 0; c < 16; c++) pk.v[c] = f2bf(xp[c * TT + t] * ga[c] + be[c]);
    u16* dst = xn + ((size_t)(b * TT + t)) * CH + g * 16;
    *(uint4*)dst = pk.q[0];
    *(uint4*)(dst + 8) = pk.q[1];
  }
}

// ---------------- GEMM helpers ----------------
// LDS tile: [128 rows][4 slots x 16B], swizzle slot ^= (row>>1)&3, rows stride CH elems in global
__device__ inline void stage512(const u16* grow0, char* ldsb, int tid) {
#pragma unroll
  for (int r = 0; r < 2; r++) {
    int chunk = tid + r * 256;
    int row = chunk >> 2;
    int slot = (chunk & 3) ^ ((row >> 1) & 3);
    gld_lds16((const char*)(grow0 + (size_t)row * CH) + slot * 16, ldsb + chunk * 16);
  }
}
__device__ inline bf16x8 frag512(const char* ldsb, int row, int g) {
  int slot = g ^ ((row >> 1) & 3);
  return *(const bf16x8*)(ldsb + row * 64 + slot * 16);
}

// EPI 0: qkv epilogue (scatter q/k channels-last per head, v channel-major t-permuted)
// EPI 1: proj epilogue (residual + bias, fp32 out)
template <int EPI>
__global__ __launch_bounds__(256) void gemm_kernel(
    const u16* __restrict__ A, const u16* __restrict__ B,
    const float* __restrict__ bias, const float* __restrict__ xres,
    u16* __restrict__ q_cl, u16* __restrict__ k_cl, u16* __restrict__ v_cm,
    float* __restrict__ outp, int Mtiles) {
  __shared__ char lds[32768];
  int tid = threadIdx.x;
  int bid = xcd_swz(blockIdx.x, Mtiles * 128);
  int mt = bid % Mtiles, nt = bid / Mtiles;
  const u16* Ab = A + (size_t)mt * 128 * CH;
  const u16* Bb = B + (size_t)nt * 128 * CH;
  int lane = tid & 63, wid = tid >> 6;
  int g = lane >> 4, r15 = lane & 15;
  int wrow = (wid >> 1) * 64, wcol = (wid & 1) * 64;
  f32x4 acc[4][4] = {};
  stage512(Ab, lds, tid);
  stage512(Bb, lds + 8192, tid);
  __syncthreads();
  for (int kt = 0; kt < CH / 32; kt++) {
    int cur = kt & 1;
    char* Ac = lds + cur * 16384;
    char* Bc = lds + 8192 + cur * 16384;
    if (kt + 1 < CH / 32) {
      char* An = lds + (cur ^ 1) * 16384;
      stage512(Ab + (kt + 1) * 32, An, tid);
      stage512(Bb + (kt + 1) * 32, An + 8192, tid);
    }
    bf16x8 af[4], bfr[4];
#pragma unroll
    for (int i = 0; i < 4; i++) af[i] = frag512(Ac, wrow + i * 16 + r15, g);
#pragma unroll
    for (int j = 0; j < 4; j++) bfr[j] = frag512(Bc, wcol + j * 16 + r15, g);
#pragma unroll
    for (int i = 0; i < 4; i++)
#pragma unroll
      for (int j = 0; j < 4; j++)
        acc[i][j] = __builtin_amdgcn_mfma_f32_16x16x32_bf16(af[i], bfr[j], acc[i][j], 0, 0, 0);
    __syncthreads();
  }
  int m0 = mt * 128 + wrow;
  if (EPI == 0) {
    int type = (m0 >> 6) % 3;
    int h = m0 / 192;
#pragma unroll
    for (int i = 0; i < 4; i++) {
      float bv[4];
#pragma unroll
      for (int r = 0; r < 4; r++) bv[r] = bias[m0 + i * 16 + g * 4 + r];
#pragma unroll
      for (int j = 0; j < 4; j++) {
        int n = nt * 128 + wcol + j * 16 + r15;
        int t = n & (TT - 1);
        int bh = (n >> 10) * NH + h;
        if (type == 2) {
          // t-permute within 64-block so attn's PV V-fragment is 16B-contiguous:
          // s=[s5 s4 g1 g0 r1 r0] -> p=[s5 g1 g0 s4 r1 r0]
          int tp = (t & ~31) | ((t & 16) >> 2) | ((t & 12) << 1) | (t & 3);
#pragma unroll
          for (int r = 0; r < 4; r++) {
            int cp = i * 16 + g * 4 + r;
            v_cm[((size_t)bh * HCH + cp) * TT + tp] = f2bf(acc[i][j][r] + bv[r]);
          }
        } else {
          union { u16 v[4]; uint2 u; } pk;
#pragma unroll
          for (int r = 0; r < 4; r++) pk.v[r] = f2bf(acc[i][j][r] + bv[r]);
          u16* dst = (type == 0 ? q_cl : k_cl) + ((size_t)bh * TT + t) * HCH + i * 16 + g * 4;
          *(uint2*)dst = pk.u;
        }
      }
    }
  } else {
#pragma unroll
    for (int i = 0; i < 4; i++) {
      float bv[4];
#pragma unroll
      for (int r = 0; r < 4; r++) bv[r] = bias[m0 + i * 16 + g * 4 + r];
#pragma unroll
      for (int j = 0; j < 4; j++) {
        int n = nt * 128 + wcol + j * 16 + r15;
        int t = n & (TT - 1);
        int bb = n >> 10;
#pragma unroll
        for (int r = 0; r < 4; r++) {
          size_t oi = ((size_t)bb * CH + m0 + i * 16 + g * 4 + r) * TT + t;
          outp[oi] = xres[oi] + acc[i][j][r] + bv[r];
        }
      }
    }
  }
}

// ---------------- flash attention ----------------
// Swapped QK^T (mfma(K,Q)) => lane holds P[s=sb*16+g*4+r][t=r15]: softmax row is
// lane-local; P-fragment for PV built fully in-register with bijection
// s(g,j) = ks*32 + (j>>2)*16 + g*4 + (j&3). V is stored t-permuted (see GEMM-0
// epilogue) so the matching V B-fragment is ONE ds_read_b128 (conflict-free,
// same XOR family as the K reads). LDS 32KB: K dbuf [2][8KB] @0, V dbuf @16384.
__device__ inline void stageKV(const u16* kb, const u16* vb, int s0,
                               char* Kd, char* Vd, int tid) {
#pragma unroll
  for (int r = 0; r < 2; r++) {
    int chunk = tid + r * 256;
    int row = chunk >> 3;
    int slot = (chunk & 7) ^ (row & 7);
    gld_lds16((const char*)(kb + (size_t)(s0 + row) * HCH) + slot * 16, Kd + chunk * 16);
    gld_lds16((const char*)(vb + (size_t)row * TT + s0) + slot * 16, Vd + chunk * 16);
  }
}

__global__ __launch_bounds__(256) void attn_kernel(
    const u16* __restrict__ q_cl, const u16* __restrict__ k_cl,
    const u16* __restrict__ v_cm, u16* __restrict__ a_cl) {
  int bid = xcd_swz(blockIdx.x, 1024);
  int bh = bid >> 3;
  int t0 = (bid & 7) * 128;
  __shared__ char lds[32768];
  int tid = threadIdx.x, lane = tid & 63, wid = tid >> 6;
  int g = lane >> 4, r15 = lane & 15;
  int tbase = (lane & 48) | ((lane & 48) >> 2);  // shfl src base: lane with r15 = g*4 (+r)
  const u16* kb0 = k_cl + (size_t)bh * TT * HCH;
  const u16* vb0 = v_cm + (size_t)bh * HCH * TT;
  // prefetch tile 0 into buf 0
  stageKV(kb0, vb0, 0, lds, lds + 16384, tid);
  // Q direct global -> registers (t = wid*32 + tb*16 + r15; d-chunk ks*32 + g*8)
  const u16* qb = q_cl + ((size_t)(bh * TT + t0)) * HCH;
  bf16x8 qf[2][2];
#pragma unroll
  for (int tb = 0; tb < 2; tb++)
#pragma unroll
    for (int ks = 0; ks < 2; ks++)
      qf[tb][ks] = *(const bf16x8*)(qb + (size_t)(wid * 32 + tb * 16 + r15) * HCH + ks * 32 + g * 8);
  __syncthreads();  // drains stage(0) + q loads
  f32x4 oacc[2][4] = {};
  float mrow[2] = {-3.0e38f, -3.0e38f};  // scaled-domain running max for t = r15 (+tb*16)
  float lrow[2] = {0.f, 0.f};
  const float SC = 0.125f * 1.44269504f;  // scale^2 * log2(e)
  for (int st = 0; st < 16; st++) {
    char* Kc = lds + (st & 1) * 8192;
    char* Vc = lds + 16384 + (st & 1) * 8192;
    if (st + 1 < 16)
      stageKV(kb0, vb0, (st + 1) * 64,
              lds + ((st + 1) & 1) * 8192, lds + 16384 + ((st + 1) & 1) * 8192, tid);
    // QK^T swapped: sacc[tb][sb] = S[s = sb*16 + g*4 + r][t = tb*16 + r15]
    f32x4 sacc[2][4] = {};
#pragma unroll
    for (int sb = 0; sb < 4; sb++) {
      int row = sb * 16 + r15;
      int sw = row & 7;
      bf16x8 k0 = *(const bf16x8*)(Kc + row * 128 + ((0 + g) ^ sw) * 16);
      bf16x8 k1 = *(const bf16x8*)(Kc + row * 128 + ((4 + g) ^ sw) * 16);
#pragma unroll
      for (int tb = 0; tb < 2; tb++) {
        sacc[tb][sb] = __builtin_amdgcn_mfma_f32_16x16x32_bf16(k0, qf[tb][0], sacc[tb][sb], 0, 0, 0);
        sacc[tb][sb] = __builtin_amdgcn_mfma_f32_16x16x32_bf16(k1, qf[tb][1], sacc[tb][sb], 0, 0, 0);
      }
    }
    // row max over this tile (raw domain; SC>0 so monotone), then defer-max check
    float mxs[2];
    bool keep = true;
#pragma unroll
    for (int tb = 0; tb < 2; tb++) {
      float m = fmaxf(fmaxf(max4(sacc[tb][0]), max4(sacc[tb][1])),
                      fmaxf(max4(sacc[tb][2]), max4(sacc[tb][3])));
      m = fmaxf(m, __shfl_xor(m, 16));
      m = fmaxf(m, __shfl_xor(m, 32));
      mxs[tb] = m * SC;
      keep = keep && (mxs[tb] <= mrow[tb] + 8.0f);
    }
    if (!__all(keep)) {
#pragma unroll
      for (int tb = 0; tb < 2; tb++) {
        float mnew = fmaxf(mrow[tb], mxs[tb]);
        float c = exp2f(mrow[tb] - mnew);
        mrow[tb] = mnew;
        lrow[tb] *= c;
#pragma unroll
        for (int r = 0; r < 4; r++) {
          float cr = __shfl(c, tbase + r);  // c for output row t-local = g*4+r
#pragma unroll
          for (int cb = 0; cb < 4; cb++) oacc[tb][cb][r] *= cr;
        }
      }
    }
    // exponentiate (fold scale into fma) + row sum; P kept in registers
    bf16x8 pf[2][2];
#pragma unroll
    for (int tb = 0; tb < 2; tb++) {
      float nm = -mrow[tb];
      float ps = 0.f;
#pragma unroll
      for (int sb = 0; sb < 4; sb++)
#pragma unroll
        for (int r = 0; r < 4; r++) {
          float e = exp2f(fmaf(sacc[tb][sb][r], SC, nm));
          sacc[tb][sb][r] = e;
          ps += e;
        }
      ps += __shfl_xor(ps, 16);
      ps += __shfl_xor(ps, 32);
      lrow[tb] += ps;
      // assemble PV A-fragments: slot j of ks holds s = ks*32 + (j>>2)*16 + g*4 + (j&3)
#pragma unroll
      for (int ks = 0; ks < 2; ks++) {
        union { u32 w[4]; bf16x8 v; } pk;
        pk.w[0] = (u32)f2bf(sacc[tb][2 * ks][0]) | ((u32)f2bf(sacc[tb][2 * ks][1]) << 16);
        pk.w[1] = (u32)f2bf(sacc[tb][2 * ks][2]) | ((u32)f2bf(sacc[tb][2 * ks][3]) << 16);
        pk.w[2] = (u32)f2bf(sacc[tb][2 * ks + 1][0]) | ((u32)f2bf(sacc[tb][2 * ks + 1][1]) << 16);
        pk.w[3] = (u32)f2bf(sacc[tb][2 * ks + 1][2]) | ((u32)f2bf(sacc[tb][2 * ks + 1][3]) << 16);
        pf[tb][ks] = pk.v;
      }
    }
    // PV: V fragment = ONE b128 per (cb,ks) thanks to the t-permuted V layout
#pragma unroll
    for (int cb = 0; cb < 4; cb++) {
      int row = cb * 16 + r15;
      int sw = row & 7;
#pragma unroll
      for (int ks = 0; ks < 2; ks++) {
        bf16x8 vv = *(const bf16x8*)(Vc + row * 128 + ((ks * 4 + g) ^ sw) * 16);
#pragma unroll
        for (int tb = 0; tb < 2; tb++)
          oacc[tb][cb] = __builtin_amdgcn_mfma_f32_16x16x32_bf16(pf[tb][ks], vv, oacc[tb][cb], 0, 0, 0);
      }
    }
    __syncthreads();  // waits this tile's LDS reads + next tile's prefetch
  }
  // write a, channels-last full [b*T+t][512]
  int b = bh >> 3, h = bh & 7;
#pragma unroll
  for (int tb = 0; tb < 2; tb++) {
    float inv = 1.0f / lrow[tb];  // for t = tb*16 + r15
#pragma unroll
    for (int r = 0; r < 4; r++) {
      float invr = __shfl(inv, tbase + r);  // for output row t-local = g*4+r
      int t = t0 + wid * 32 + tb * 16 + g * 4 + r;
      u16* dst = a_cl + ((size_t)(b * TT + t)) * CH + h * HCH;
#pragma unroll
      for (int cb = 0; cb < 4; cb++)
        dst[cb * 16 + r15] = f2bf(oacc[tb][cb][r] * invr);
    }
  }
}

// ---------------- launcher ----------------
extern "C" void kernel_launch(void* const* d_in, const int* in_sizes, int n_in,
                              void* d_out, int out_size, void* d_ws, size_t ws_size,
                              hipStream_t stream) {
  const float* x = (const float*)d_in[0];
  const float* gamma = (const float*)d_in[1];
  const float* beta = (const float*)d_in[2];
  const float* w_qkv = (const float*)d_in[3];
  const float* b_qkv = (const float*)d_in[4];
  const float* w_proj = (const float*)d_in[5];
  const float* b_proj = (const float*)d_in[6];
  float* out = (float*)d_out;
  char* ws = (char*)d_ws;
  u16* wqb = (u16*)ws;                      // 1.5 MB
  u16* wpb = (u16*)(ws + 0x180000);         // 0.5 MB
  u16* xn  = (u16*)(ws + 0x200000);         // 16 MB (reused as a_cl)
  u16* qcl = (u16*)(ws + 0x1200000);        // 16 MB
  u16* kcl = (u16*)(ws + 0x2200000);        // 16 MB
  u16* vcm = (u16*)(ws + 0x3200000);        // 16 MB
  hipLaunchKernelGGL(castw_kernel, dim3(3072), dim3(256), 0, stream, w_qkv, w_proj, wqb, wpb);
  hipLaunchKernelGGL(gn_kernel, dim3(512), dim3(256), 0, stream, x, gamma, beta, xn);
  hipLaunchKernelGGL(gemm_kernel<0>, dim3(12 * 128), dim3(256), 0, stream,
                     wqb, xn, b_qkv, (const float*)nullptr,
                     qcl, kcl, vcm, (float*)nullptr, 12);
  hipLaunchKernelGGL(attn_kernel, dim3(1024), dim3(256), 0, stream, qcl, kcl, vcm, xn);
  hipLaunchKernelGGL(gemm_kernel<1>, dim3(4 * 128), dim3(256), 0, stream,
                     wpb, xn, b_proj, x,
                     (u16*)nullptr, (u16*)nullptr, (u16*)nullptr, out, 4);
}